// Round 15
// baseline (10406.213 us; speedup 1.0000x reference)
//
#include <hip/hip_runtime.h>
#include <cstdint>
#include <cstddef>

// ---------------------------------------------------------------------------
// DeepCNNLSTM_EncoderMOE on MI355X (gfx950)
// Round 15: LSTM v10 — 2 batches per WG (32 WGs). The 200 KB/step W_hh
// spill-stream is batch-invariant; amortize it over 2 batch elements.
// Gate update split: half0 owns (batch0,d), half1 owns (batch1,d).
// Pipeline = R14 (verified 496 us non-LSTM).
// ---------------------------------------------------------------------------

#define DEVI __device__ __forceinline__

typedef _Float16 f16;
typedef _Float16 f16x8 __attribute__((ext_vector_type(8)));
typedef _Float16 f16x2 __attribute__((ext_vector_type(2)));
typedef float    f32x4 __attribute__((ext_vector_type(4)));
typedef unsigned int u32;
typedef unsigned short u16;

static constexpr int B   = 64;
static constexpr int T   = 512;
static constexpr int NC  = 10;
static constexpr int NU  = 192;

// ---- workspace layout (bytes) ----
constexpr size_t SZ_WS1 = (size_t)5*64*32*2;
constexpr size_t SZ_WS2 = (size_t)5*128*64*2;
constexpr size_t SZ_WS3 = (size_t)5*256*128*2;
constexpr size_t SZ_WE1 = 8*SZ_WS1;
constexpr size_t SZ_WE2 = 8*SZ_WS2;
constexpr size_t SZ_WE3 = 8*SZ_WS3;
constexpr size_t SZ_WR  = (size_t)5*128*32*2;
constexpr size_t SZ_WIH = (size_t)1024*256*2;
constexpr size_t SZ_WHH = (size_t)128*1024*4;
constexpr size_t SZ_ACT0 = (size_t)B*T*32*2;
constexpr size_t SZ_RACT = (size_t)B*T*128*2;
constexpr size_t SZ_AMIX = (size_t)B*T*256*2;
constexpr size_t SZ_CONV = (size_t)NU*T*256*2;
constexpr size_t SZ_A1   = (size_t)NU*T*64*2;
constexpr size_t SZ_A2   = (size_t)NU*T*128*2;
constexpr size_t SZ_U    = (size_t)B*T*1024*2;     // aliases CONV+A1+A2
constexpr size_t SZ_STAT = (size_t)NU*8*2*4;
constexpr size_t SZ_STATR= (size_t)B*8*2*4;
constexpr size_t SZ_RH   = (size_t)B*128*4;
constexpr size_t SZ_EIDX = (size_t)B*2*4;
constexpr size_t SZ_SWT  = (size_t)B*2*4;
constexpr size_t SZ_HT   = (size_t)B*256*4;

constexpr size_t OFF_WS1  = 0;
constexpr size_t OFF_WS2  = OFF_WS1 + SZ_WS1;
constexpr size_t OFF_WS3  = OFF_WS2 + SZ_WS2;
constexpr size_t OFF_WE1  = OFF_WS3 + SZ_WS3;
constexpr size_t OFF_WE2  = OFF_WE1 + SZ_WE1;
constexpr size_t OFF_WE3  = OFF_WE2 + SZ_WE2;
constexpr size_t OFF_WR   = OFF_WE3 + SZ_WE3;
constexpr size_t OFF_WIH  = OFF_WR  + SZ_WR;
constexpr size_t OFF_WHH  = OFF_WIH + SZ_WIH;
constexpr size_t OFF_ACT0 = OFF_WHH + SZ_WHH;
constexpr size_t OFF_RACT = OFF_ACT0 + SZ_ACT0;
constexpr size_t OFF_AMIX = OFF_RACT + SZ_RACT;
constexpr size_t OFF_CONV = OFF_AMIX + SZ_AMIX;
constexpr size_t OFF_A1   = OFF_CONV + SZ_CONV;
constexpr size_t OFF_A2   = OFF_A1 + SZ_A1;
constexpr size_t OFF_U    = OFF_CONV;              // alias
constexpr size_t OFF_STAT = OFF_A2 + SZ_A2;
constexpr size_t OFF_STATR= OFF_STAT + SZ_STAT;
constexpr size_t OFF_RH   = OFF_STATR + SZ_STATR;
constexpr size_t OFF_EIDX = OFF_RH + SZ_RH;
constexpr size_t OFF_SWT  = OFF_EIDX + SZ_EIDX;
constexpr size_t OFF_HT   = OFF_SWT + SZ_SWT;
constexpr size_t WS_TOTAL = OFF_HT + SZ_HT;

static_assert(SZ_U <= SZ_CONV + SZ_A1 + SZ_A2, "U alias overflow");

DEVI float geluf(float x){ return 0.5f*x*(1.f + erff(x*0.70710678118654752f)); }
DEVI float fsig(float x){ return 1.f/(1.f + __expf(-x)); }
DEVI float ftanh(float x){ float e = __expf(-2.f*x); return (1.f-e)/(1.f+e); }

// ---------------------------------------------------------------------------
// Weight prep (unchanged, verified)
// ---------------------------------------------------------------------------
DEVI void fill_convw(f16* dst, const float* src, int COUT, int CI, int CIP, int idx){
  int s  = idx / (COUT*CIP);
  int r  = idx - s*(COUT*CIP);
  int co = r / CIP;
  int ci = r - co*CIP;
  float v = (ci < CI) ? src[((size_t)co*CI + ci)*5 + s] : 0.f;
  dst[idx] = (f16)v;
}

__global__ __launch_bounds__(256) void k_prep_w(
    const float* eW1, const float* eW2, const float* eW3,
    const float* sW1, const float* sW2, const float* sW3, const float* rW,
    const float* Wih, const float* Whh, char* ws)
{
  int i = blockIdx.x*256 + threadIdx.x;
  if (i < 10240){ fill_convw((f16*)(ws+OFF_WS1), sW1, 64, 16, 32, i); return; } i -= 10240;
  if (i < 40960){ fill_convw((f16*)(ws+OFF_WS2), sW2, 128, 64, 64, i); return; } i -= 40960;
  if (i < 163840){ fill_convw((f16*)(ws+OFF_WS3), sW3, 256, 128, 128, i); return; } i -= 163840;
  if (i < 81920){ int e=i/10240, r=i-e*10240;
    fill_convw((f16*)(ws+OFF_WE1)+ (size_t)e*10240, eW1 + (size_t)e*64*16*5, 64, 16, 32, r); return; } i -= 81920;
  if (i < 327680){ int e=i/40960, r=i-e*40960;
    fill_convw((f16*)(ws+OFF_WE2)+ (size_t)e*40960, eW2 + (size_t)e*128*64*5, 128, 64, 64, r); return; } i -= 327680;
  if (i < 1310720){ int e=i/163840, r=i-e*163840;
    fill_convw((f16*)(ws+OFF_WE3)+ (size_t)e*163840, eW3 + (size_t)e*163840, 256, 128, 128, r); return; } i -= 1310720;
  if (i < 20480){ fill_convw((f16*)(ws+OFF_WR), rW, 128, 16, 32, i); return; } i -= 20480;
  if (i < 262144){ // W_ih (256,1024) -> [j][k]
    int j = i >> 8, k = i & 255;
    ((f16*)(ws+OFF_WIH))[i] = (f16)Wih[(size_t)k*1024 + j]; return; } i -= 262144;
  if (i < 131072){ // W_hh -> packed row-pairs [pair][1024]
    int i2 = i >> 10, j = i & 1023;
    f16 a = (f16)Whh[(size_t)(2*i2)*1024 + j];
    f16 b = (f16)Whh[(size_t)(2*i2+1)*1024 + j];
    u32 u = (u32)__builtin_bit_cast(unsigned short, a)
          | ((u32)__builtin_bit_cast(unsigned short, b) << 16);
    ((u32*)(ws+OFF_WHH))[i] = u; return; }
}

__global__ __launch_bounds__(256) void k_prep_x(const float* __restrict__ x, char* ws){
  int idx = blockIdx.x*256 + threadIdx.x;
  if (idx >= B*T*32) return;
  int b = idx/(T*32); int r = idx - b*(T*32); int t = r >> 5; int c = r & 31;
  f16 v = (c < 16) ? (f16)x[((size_t)b*16 + c)*T + t] : (f16)0.f;
  ((f16*)(ws+OFF_ACT0))[idx] = v;
}

// ---------------------------------------------------------------------------
// Fused layer (verified R12/R14)
// ---------------------------------------------------------------------------
template<int CIN, int COUT_BLK, int CPG, bool GAP>
__global__ __launch_bounds__(512) void k_layer(
    const f16* __restrict__ act, long actUnitStride,
    const f16* __restrict__ wtS, const f16* __restrict__ wtE, long wtEStride,
    const int* __restrict__ eidx,
    const float* __restrict__ gS, const float* __restrict__ bS,
    const float* __restrict__ gE, const float* __restrict__ bE,
    int COUT_TOTAL,
    f16* __restrict__ outp, long outUnitStride, int outStride,
    float* __restrict__ rhOut)
{
  constexpr int CH8  = COUT_BLK/8;
  constexpr int NG   = COUT_BLK/CPG;
  constexpr int CPW  = CPG/8;
  constexpr int NF   = (COUT_BLK >= 64) ? 4 : COUT_BLK/16;
  constexpr int NPASS = COUT_BLK/(NF*16);
  constexpr int ROWSTEP = 512/CH8;
  constexpr int ITERS   = T/ROWSTEP;

  int u = blockIdx.x, hf = blockIdx.y;
  int s_ = u >> 6, b = u & 63;
  const f16* wt = wtS;
  const float* gamma = gS; const float* beta = bS;
  if (eidx && s_ < 2){
    int e = eidx[b*2 + s_];
    wt    = wtE + (size_t)e*wtEStride;
    gamma = gE + (size_t)e*COUT_TOTAL;
    beta  = bE + (size_t)e*COUT_TOTAL;
  }
  gamma += hf*COUT_BLK; beta += hf*COUT_BLK;
  const f16* abase = act + (actUnitStride ? (size_t)u*actUnitStride
                                          : (size_t)b*T*CIN);
  int wcol0 = hf*COUT_BLK;

  __shared__ f16 tile[T*COUT_BLK];
  __shared__ float cpart[8][CH8][2];
  __shared__ float mr[NG][2];
  __shared__ float gcol[GAP ? 8 : 1][GAP ? CH8 : 1][8];

  int tid = threadIdx.x;
  int wave = tid >> 6, lane = tid & 63;
  int lr = lane & 15, lk = lane >> 4;

  // ---- conv phase ----
  for (int mt = wave; mt < 32; mt += 8){
    int trow = mt*16 + lr;
    #pragma unroll
    for (int np = 0; np < NPASS; ++np){
      f32x4 acc[NF];
      #pragma unroll
      for (int nf=0; nf<NF; ++nf) acc[nf] = f32x4{0.f,0.f,0.f,0.f};
      #pragma unroll
      for (int sh = 0; sh < 5; ++sh){
        int tg = trow + sh - 2;
        bool valid = (unsigned)tg < (unsigned)T;
        const f16* arow = abase + (long)tg*CIN + lk*8;
        #pragma unroll
        for (int c0=0; c0<CIN; c0+=32){
          f16x8 af = {(f16)0,(f16)0,(f16)0,(f16)0,(f16)0,(f16)0,(f16)0,(f16)0};
          if (valid) af = *(const f16x8*)(arow + c0);
          #pragma unroll
          for (int nf=0; nf<NF; ++nf){
            int col = wcol0 + np*NF*16 + nf*16 + lr;
            f16x8 bf = *(const f16x8*)(wt + ((size_t)sh*COUT_TOTAL + col)*CIN + c0 + lk*8);
            acc[nf] = __builtin_amdgcn_mfma_f32_16x16x32_f16(af, bf, acc[nf], 0, 0, 0);
          }
        }
      }
      #pragma unroll
      for (int nf=0; nf<NF; ++nf)
        #pragma unroll
        for (int r=0; r<4; ++r)
          tile[(size_t)(mt*16 + lk*4 + r)*COUT_BLK + np*NF*16 + nf*16 + lr] = (f16)acc[nf][r];
    }
  }
  __syncthreads();

  // ---- stats phase ----
  int chunk = tid & (CH8-1);
  int row0  = tid / CH8;
  float sum = 0.f, ss = 0.f;
  #pragma unroll
  for (int k=0; k<ITERS; ++k){
    int row = row0 + k*ROWSTEP;
    f16x8 xv = *(const f16x8*)(tile + (size_t)row*COUT_BLK + chunk*8);
    #pragma unroll
    for (int e=0;e<8;++e){ float f = (float)xv[e]; sum += f; ss += f*f; }
  }
  #pragma unroll
  for (int mk=CH8; mk<=32; mk<<=1){ sum += __shfl_xor(sum, mk); ss += __shfl_xor(ss, mk); }
  if (lane < CH8){ cpart[wave][lane][0] = sum; cpart[wave][lane][1] = ss; }
  __syncthreads();
  if (tid < NG){
    float S = 0.f, Q = 0.f;
    for (int w2=0; w2<8; ++w2)
      for (int cc=0; cc<CPW; ++cc){ S += cpart[w2][tid*CPW+cc][0]; Q += cpart[w2][tid*CPW+cc][1]; }
    constexpr float N = (float)(CPG*T);
    float m = S/N, var = Q/N - m*m;
    mr[tid][0] = m; mr[tid][1] = rsqrtf(var + 1e-5f);
  }
  __syncthreads();

  // ---- apply phase ----
  int g = chunk / CPW;
  float m = mr[g][0], rstd = mr[g][1];
  float gm[8], bt[8];
  #pragma unroll
  for (int e=0;e<8;++e){ gm[e] = gamma[chunk*8+e]; bt[e] = beta[chunk*8+e]; }
  float cs[8] = {0.f,0.f,0.f,0.f,0.f,0.f,0.f,0.f};
  f16* obase = outp ? (outp + (size_t)u*outUnitStride + hf*COUT_BLK) : nullptr;
  #pragma unroll
  for (int k=0; k<ITERS; ++k){
    int row = row0 + k*ROWSTEP;
    f16x8 xv = *(const f16x8*)(tile + (size_t)row*COUT_BLK + chunk*8);
    f16x8 h8;
    #pragma unroll
    for (int e=0;e<8;++e){
      float xn = ((float)xv[e]-m)*rstd*gm[e] + bt[e];
      float o = geluf(xn);
      if constexpr (GAP) cs[e] += o; else h8[e] = (f16)o;
    }
    if constexpr (!GAP)
      *(f16x8*)(obase + (size_t)row*outStride + chunk*8) = h8;
  }
  if constexpr (GAP){
    #pragma unroll
    for (int mk=CH8; mk<=32; mk<<=1)
      #pragma unroll
      for (int e=0;e<8;++e) cs[e] += __shfl_xor(cs[e], mk);
    if (lane < CH8)
      #pragma unroll
      for (int e=0;e<8;++e) gcol[wave][lane][e] = cs[e];
    __syncthreads();
    if (tid < COUT_BLK){
      int c = tid >> 3, e = tid & 7;
      float tot = 0.f;
      for (int w2=0; w2<8; ++w2) tot += gcol[w2][c][e];
      rhOut[b*128 + hf*COUT_BLK + tid] = tot * (1.f/(float)T);
    }
  }
}

// ---------------------------------------------------------------------------
// Fused mix + W_ih GEMM (verified R13/R14)
// ---------------------------------------------------------------------------
__global__ __launch_bounds__(512) void k_convmix(
    const f16* __restrict__ conv, const float* __restrict__ swt,
    const f16* __restrict__ wih, const float* __restrict__ bias,
    f16* __restrict__ U)
{
  int tt = blockIdx.x;
  int b  = blockIdx.y;
  int t0 = tt*64;

  __shared__ f16 amixT[64][264];

  float w0 = swt[b*2], w1 = swt[b*2+1];
  const f16* s0 = conv + (size_t)b*T*256;
  const f16* s1 = conv + (size_t)(64+b)*T*256;
  const f16* s2 = conv + (size_t)(128+b)*T*256;

  int tid = threadIdx.x;
  for (int i = tid; i < 64*32; i += 512){
    int row = i >> 5, ch = i & 31;
    size_t off = (size_t)(t0+row)*256 + ch*8;
    f16x8 x0 = *(const f16x8*)(s0+off);
    f16x8 x1 = *(const f16x8*)(s1+off);
    f16x8 x2 = *(const f16x8*)(s2+off);
    f16x8 h8;
    #pragma unroll
    for (int e=0;e<8;++e)
      h8[e] = (f16)(w0*(float)x0[e] + w1*(float)x1[e] + (float)x2[e]);
    *(f16x8*)(&amixT[row][ch*8]) = h8;
  }
  __syncthreads();

  int wave = tid >> 6, lane = tid & 63;
  int lr = lane & 15, lk = lane >> 4;
  f16* ob = U + ((size_t)b*T + t0)*1024;

  for (int tk = wave; tk < 64; tk += 8){
    int mtile = tk >> 4, panel = tk & 15;
    int n0 = panel*64;
    f32x4 acc[4];
    #pragma unroll
    for (int nf=0; nf<4; ++nf) acc[nf] = f32x4{0.f,0.f,0.f,0.f};
    #pragma unroll
    for (int c0=0; c0<256; c0+=32){
      f16x8 af = *(const f16x8*)(&amixT[mtile*16 + lr][c0 + lk*8]);
      #pragma unroll
      for (int nf=0; nf<4; ++nf){
        int col = n0 + nf*16 + lr;
        f16x8 bf = *(const f16x8*)(wih + (size_t)col*256 + c0 + lk*8);
        acc[nf] = __builtin_amdgcn_mfma_f32_16x16x32_f16(af, bf, acc[nf], 0, 0, 0);
      }
    }
    #pragma unroll
    for (int nf=0; nf<4; ++nf){
      int col = n0 + nf*16 + lr;
      float bv = bias[col];
      #pragma unroll
      for (int r=0; r<4; ++r){
        int trw = mtile*16 + lk*4 + r;
        ob[(size_t)trw*1024 + col] = (f16)(acc[nf][r] + bv);
      }
    }
  }
}

// ---------------------------------------------------------------------------
// Router MLP (unchanged, verified)
// ---------------------------------------------------------------------------
__global__ __launch_bounds__(128) void k_router(
    const float* __restrict__ rh,
    const float* __restrict__ m1W, const float* __restrict__ m1b,
    const float* __restrict__ lng, const float* __restrict__ lnb,
    const float* __restrict__ m2W, const float* __restrict__ m2b,
    const float* __restrict__ gW,  const float* __restrict__ gb,
    int* __restrict__ eidx, float* __restrict__ swt)
{
  int b = blockIdx.x, j = threadIdx.x;
  __shared__ float sbuf[128];
  __shared__ float red[4];
  __shared__ float z2[64];
  sbuf[j] = rh[b*128 + j];
  __syncthreads();
  float acc = m1b[j];
  for (int k=0; k<128; ++k) acc += sbuf[k]*m1W[k*128 + j];
  float s1 = acc, s2 = acc*acc;
  #pragma unroll
  for (int off=32; off; off>>=1){ s1 += __shfl_down(s1, off); s2 += __shfl_down(s2, off); }
  int wid = j >> 6, lane = j & 63;
  if (lane == 0){ red[wid] = s1; red[2+wid] = s2; }
  __syncthreads();
  float S = red[0]+red[1], Q = red[2]+red[3];
  float m = S*(1.f/128.f), var = Q*(1.f/128.f) - m*m;
  float xn = (acc - m)*rsqrtf(var + 1e-5f)*lng[j] + lnb[j];
  float ge = geluf(xn);
  __syncthreads();
  sbuf[j] = ge;
  __syncthreads();
  if (j < 64){
    float a = m2b[j];
    for (int k=0; k<128; ++k) a += sbuf[k]*m2W[k*64 + j];
    z2[j] = a;
  }
  __syncthreads();
  if (j == 0){
    float lg[8];
    for (int e=0; e<8; ++e){
      float a = gb[e];
      for (int k=0; k<64; ++k) a += z2[k]*gW[k*8 + e];
      lg[e] = a;
    }
    float mx = lg[0];
    for (int e=1; e<8; ++e) mx = fmaxf(mx, lg[e]);
    float p[8], sum = 0.f;
    for (int e=0; e<8; ++e){ p[e] = __expf(lg[e]-mx); sum += p[e]; }
    float inv = 1.f/sum;
    for (int e=0; e<8; ++e) p[e] *= inv;
    int i1 = 0;
    for (int e=1; e<8; ++e) if (p[e] > p[i1]) i1 = e;
    int i2 = -1;
    for (int e=0; e<8; ++e){ if (e==i1) continue; if (i2 < 0 || p[e] > p[i2]) i2 = e; }
    float s = p[i1] + p[i2] + 1e-9f;
    eidx[b*2]   = i1;  swt[b*2]   = p[i1]/s;
    eidx[b*2+1] = i2;  swt[b*2+1] = p[i2]/s;
  }
}

// ---------------------------------------------------------------------------
// Persistent LSTM v10: 32 WGs, 2 batches per WG. Same weight layout as the
// verified R5 kernel (PV5=100 VGPR pairs/col + PLQ=7 LDS quads/col); each
// loaded weight feeds dot2 against BOTH batches' h. Thread (half,d) owns
// the state of (batch=half, dim=d); gbX exchanges cross-half gates.
// ---------------------------------------------------------------------------
constexpr int PV5 = 100;
constexpr int PLQ = 7;

DEVI float dot2acc(u32 wu, u32 hu, float acc){
#if __has_builtin(__builtin_amdgcn_fdot2)
  return __builtin_amdgcn_fdot2(__builtin_bit_cast(f16x2, wu),
                                __builtin_bit_cast(f16x2, hu), acc, false);
#else
  f16x2 a = __builtin_bit_cast(f16x2, wu), b = __builtin_bit_cast(f16x2, hu);
  return acc + (float)a.x*(float)b.x + (float)a.y*(float)b.y;
#endif
}

__global__ __attribute__((amdgpu_flat_work_group_size(512,512), amdgpu_waves_per_eu(2,2)))
void k_lstm(const u32* __restrict__ whh, const f16* __restrict__ U,
            float* __restrict__ hTout)
{
  int bb = blockIdx.x;            // 0..31
  int b0 = bb*2, b1 = bb*2 + 1;
  int j = threadIdx.x;
  int d = j & 255, half = j >> 8;
  int colA = half*256 + d;        // i (half0) / f (half1)
  int colB = 512 + colA;          // g (half0) / o (half1)

  __shared__ u32 wl[PLQ*4*1024];               // 112 KB: pairs [100,128)
  __shared__ __align__(16) u32 hbuf0[2][128];  // batch0 packed h (dbuf)
  __shared__ __align__(16) u32 hbuf1[2][128];  // batch1
  __shared__ float gbX[4][256];   // [0]=f0 [1]=o0 [2]=i1 [3]=g1

  u32 wA[PV5], wB[PV5];
  #pragma unroll
  for (int i=0; i<PV5; ++i){
    wA[i] = whh[(size_t)i*1024 + colA];
    wB[i] = whh[(size_t)i*1024 + colB];
  }
  for (int idx = j; idx < PLQ*4*1024; idx += 512){
    int p = idx >> 10, c = idx & 1023;
    wl[idx] = whh[(size_t)(PV5+p)*1024 + c];
  }
  if (j < 128){ hbuf0[0][j] = 0u; hbuf1[0][j] = 0u; }

  float cst = 0.f, hst = 0.f;     // state of (batch=half, dim=d)
  const f16* Ub0 = U + (size_t)b0*T*1024;
  const f16* Ub1 = U + (size_t)b1*T*1024;
  float uA0 = (float)Ub0[colA], uB0 = (float)Ub0[colB];
  float uA1 = (float)Ub1[colA], uB1 = (float)Ub1[colB];
  __syncthreads();

  int cur = 0;
  for (int t=0; t<T; ++t){
    float aA0 = uA0, aB0 = uB0, aA1 = uA1, aB1 = uB1;
    if (t+1 < T){
      const f16* u0 = Ub0 + (size_t)(t+1)*1024;
      const f16* u1 = Ub1 + (size_t)(t+1)*1024;
      uA0 = (float)u0[colA]; uB0 = (float)u0[colB];
      uA1 = (float)u1[colA]; uB1 = (float)u1[colB];
    }
    const uint4* hp0 = (const uint4*)hbuf0[cur];
    const uint4* hp1 = (const uint4*)hbuf1[cur];
    #pragma unroll
    for (int q=0; q<PV5/4; ++q){
      uint4 h0 = hp0[q], h1 = hp1[q];
      aA0 = dot2acc(wA[4*q+0], h0.x, aA0); aA1 = dot2acc(wA[4*q+0], h1.x, aA1);
      aB0 = dot2acc(wB[4*q+0], h0.x, aB0); aB1 = dot2acc(wB[4*q+0], h1.x, aB1);
      aA0 = dot2acc(wA[4*q+1], h0.y, aA0); aA1 = dot2acc(wA[4*q+1], h1.y, aA1);
      aB0 = dot2acc(wB[4*q+1], h0.y, aB0); aB1 = dot2acc(wB[4*q+1], h1.y, aB1);
      aA0 = dot2acc(wA[4*q+2], h0.z, aA0); aA1 = dot2acc(wA[4*q+2], h1.z, aA1);
      aB0 = dot2acc(wB[4*q+2], h0.z, aB0); aB1 = dot2acc(wB[4*q+2], h1.z, aB1);
      aA0 = dot2acc(wA[4*q+3], h0.w, aA0); aA1 = dot2acc(wA[4*q+3], h1.w, aA1);
      aB0 = dot2acc(wB[4*q+3], h0.w, aB0); aB1 = dot2acc(wB[4*q+3], h1.w, aB1);
    }
    #pragma unroll
    for (int k=0; k<PLQ; ++k){
      uint4 h0 = hp0[PV5/4 + k], h1 = hp1[PV5/4 + k];
      u32 a0 = wl[(4*k+0)*1024 + colA], c0 = wl[(4*k+0)*1024 + colB];
      u32 a1 = wl[(4*k+1)*1024 + colA], c1 = wl[(4*k+1)*1024 + colB];
      u32 a2 = wl[(4*k+2)*1024 + colA], c2 = wl[(4*k+2)*1024 + colB];
      u32 a3 = wl[(4*k+3)*1024 + colA], c3 = wl[(4*k+3)*1024 + colB];
      aA0 = dot2acc(a0, h0.x, aA0); aA1 = dot2acc(a0, h1.x, aA1);
      aB0 = dot2acc(c0, h0.x, aB0); aB1 = dot2acc(c0, h1.x, aB1);
      aA0 = dot2acc(a1, h0.y, aA0); aA1 = dot2acc(a1, h1.y, aA1);
      aB0 = dot2acc(c1, h0.y, aB0); aB1 = dot2acc(c1, h1.y, aB1);
      aA0 = dot2acc(a2, h0.z, aA0); aA1 = dot2acc(a2, h1.z, aA1);
      aB0 = dot2acc(c2, h0.z, aB0); aB1 = dot2acc(c2, h1.z, aB1);
      aA0 = dot2acc(a3, h0.w, aA0); aA1 = dot2acc(a3, h1.w, aA1);
      aB0 = dot2acc(c3, h0.w, aB0); aB1 = dot2acc(c3, h1.w, aB1);
    }
    // cross-half gate exchange:
    // half0 computed (i,g) for both batches; half1 computed (f,o) for both.
    if (half){ gbX[0][d] = aA0; gbX[1][d] = aB0; }   // f0, o0
    else     { gbX[2][d] = aA1; gbX[3][d] = aB1; }   // i1, g1
    __syncthreads();
    float gi, gf, gg, go;
    if (!half){ gi = aA0;        gg = aB0;        gf = gbX[0][d]; go = gbX[1][d]; }
    else      { gi = gbX[2][d];  gg = gbX[3][d];  gf = aA1;       go = aB1;       }
    cst = fsig(gf)*cst + fsig(gi)*ftanh(gg);
    hst = fsig(go)*ftanh(cst);
    u16* hn = half ? (u16*)hbuf1[cur^1] : (u16*)hbuf0[cur^1];
    hn[d] = __builtin_bit_cast(u16, (f16)hst);
    __syncthreads();
    cur ^= 1;
  }
  hTout[(half ? b1 : b0)*256 + d] = hst;
}

__global__ __launch_bounds__(256) void k_head(const float* __restrict__ hT,
    const float* __restrict__ Wc, const float* __restrict__ bc,
    float* __restrict__ out)
{
  int b = blockIdx.x, j = threadIdx.x;
  __shared__ float hs[256];
  hs[j] = hT[b*256 + j];
  __syncthreads();
  if (j < NC){
    float a = bc[j];
    for (int k=0; k<256; ++k) a += hs[k]*Wc[k*NC + j];
    out[b*NC + j] = a;
  }
}

// ---------------------------------------------------------------------------
extern "C" void kernel_launch(void* const* d_in, const int* in_sizes, int n_in,
                              void* d_out, int out_size, void* d_ws, size_t ws_size,
                              hipStream_t stream)
{
  if (ws_size < WS_TOTAL) return;

  const float* x    = (const float*)d_in[0];
  const float* eW1  = (const float*)d_in[1];
  const float* eg1  = (const float*)d_in[2];
  const float* eb1  = (const float*)d_in[3];
  const float* eW2  = (const float*)d_in[4];
  const float* eg2  = (const float*)d_in[5];
  const float* eb2  = (const float*)d_in[6];
  const float* eW3  = (const float*)d_in[7];
  const float* eg3  = (const float*)d_in[8];
  const float* eb3  = (const float*)d_in[9];
  const float* sW1  = (const float*)d_in[10];
  const float* sg1  = (const float*)d_in[11];
  const float* sb1  = (const float*)d_in[12];
  const float* sW2  = (const float*)d_in[13];
  const float* sg2  = (const float*)d_in[14];
  const float* sb2  = (const float*)d_in[15];
  const float* sW3  = (const float*)d_in[16];
  const float* sg3  = (const float*)d_in[17];
  const float* sb3  = (const float*)d_in[18];
  const float* rW   = (const float*)d_in[19];
  const float* rg   = (const float*)d_in[20];
  const float* rb   = (const float*)d_in[21];
  const float* rm1W = (const float*)d_in[22];
  const float* rm1b = (const float*)d_in[23];
  const float* rlng = (const float*)d_in[24];
  const float* rlnb = (const float*)d_in[25];
  const float* rm2W = (const float*)d_in[26];
  const float* rm2b = (const float*)d_in[27];
  const float* gW   = (const float*)d_in[28];
  const float* gb   = (const float*)d_in[29];
  const float* Wih  = (const float*)d_in[30];
  const float* Whh  = (const float*)d_in[31];
  const float* blst = (const float*)d_in[32];
  const float* Wc   = (const float*)d_in[33];
  const float* bc   = (const float*)d_in[34];

  char* ws = (char*)d_ws;
  f16*  ws1   = (f16*)(ws + OFF_WS1);
  f16*  ws2   = (f16*)(ws + OFF_WS2);
  f16*  ws3   = (f16*)(ws + OFF_WS3);
  f16*  we1   = (f16*)(ws + OFF_WE1);
  f16*  we2   = (f16*)(ws + OFF_WE2);
  f16*  we3   = (f16*)(ws + OFF_WE3);
  f16*  wr    = (f16*)(ws + OFF_WR);
  f16*  wih   = (f16*)(ws + OFF_WIH);
  u32*  whh   = (u32*)(ws + OFF_WHH);
  f16*  act0  = (f16*)(ws + OFF_ACT0);
  f16*  convb = (f16*)(ws + OFF_CONV);
  f16*  a1    = (f16*)(ws + OFF_A1);
  f16*  a2    = (f16*)(ws + OFF_A2);
  f16*  Ubuf  = (f16*)(ws + OFF_U);
  float* rh    = (float*)(ws + OFF_RH);
  int*   eidx  = (int*)(ws + OFF_EIDX);
  float* swt   = (float*)(ws + OFF_SWT);
  float* hTb   = (float*)(ws + OFF_HT);

  // ---- prep ----
  k_prep_w<<<(2349056 + 255)/256, 256, 0, stream>>>(eW1,eW2,eW3,sW1,sW2,sW3,rW,Wih,Whh,ws);
  k_prep_x<<<(B*T*32 + 255)/256, 256, 0, stream>>>(x, ws);

  // ---- router: fused conv+GN+GELU+GAP (2 chan-halves) -> rh -> MLP ----
  k_layer<32,64,16,true><<<dim3(64,2), 512, 0, stream>>>(
      act0, 0L, wr, nullptr, 0L, nullptr, rg, rb, nullptr, nullptr, 128,
      nullptr, 0L, 0, rh);
  k_router<<<B, 128, 0, stream>>>(rh, rm1W, rm1b, rlng, rlnb, rm2W, rm2b, gW, gb, eidx, swt);

  // ---- fused layers (channel-split grids: 384/384/768 blocks) ----
  k_layer<32,32,8,false><<<dim3(NU,2), 512, 0, stream>>>(
      act0, 0L, ws1, we1, (long)(5*64*32), eidx, sg1, sb1, eg1, eb1, 64,
      a1, (long)T*64, 64, nullptr);
  k_layer<64,64,16,false><<<dim3(NU,2), 512, 0, stream>>>(
      a1, (long)T*64, ws2, we2, (long)(5*128*64), eidx, sg2, sb2, eg2, eb2, 128,
      a2, (long)T*128, 128, nullptr);
  k_layer<128,64,32,false><<<dim3(NU,4), 512, 0, stream>>>(
      a2, (long)T*128, ws3, we3, (long)(5*256*128), eidx, sg3, sb3, eg3, eb3, 256,
      convb, (long)T*256, 256, nullptr);

  // ---- fused mix + W_ih GEMM -> U ----
  k_convmix<<<dim3(8,64), 512, 0, stream>>>(convb, swt, wih, blst, Ubuf);

  // ---- LSTM (2 batches per WG) ----
  k_lstm<<<32, 512, 0, stream>>>(whh, Ubuf, hTb);
  k_head<<<B, 256, 0, stream>>>(hTb, Wc, bc, (float*)d_out);
}

// Round 16
// 1358.871 us; speedup vs baseline: 7.6580x; 7.6580x over previous
//
#include <hip/hip_runtime.h>
#include <cstdint>
#include <cstddef>

// ---------------------------------------------------------------------------
// DeepCNNLSTM_EncoderMOE on MI355X (gfx950)
// Round 16: revert to R14 (verified best, 1359 us). LSTM = R5 optimum
// (863 us, 4x reproduced); pipeline = R12 channel-split fusion + R13 convmix.
// R15's 2-batch amortization refuted (spill reloads per-use; 32-WG grid).
// ---------------------------------------------------------------------------

#define DEVI __device__ __forceinline__

typedef _Float16 f16;
typedef _Float16 f16x8 __attribute__((ext_vector_type(8)));
typedef _Float16 f16x2 __attribute__((ext_vector_type(2)));
typedef float    f32x4 __attribute__((ext_vector_type(4)));
typedef unsigned int u32;
typedef unsigned short u16;

static constexpr int B   = 64;
static constexpr int T   = 512;
static constexpr int NC  = 10;
static constexpr int NU  = 192;

// ---- workspace layout (bytes) ----
constexpr size_t SZ_WS1 = (size_t)5*64*32*2;
constexpr size_t SZ_WS2 = (size_t)5*128*64*2;
constexpr size_t SZ_WS3 = (size_t)5*256*128*2;
constexpr size_t SZ_WE1 = 8*SZ_WS1;
constexpr size_t SZ_WE2 = 8*SZ_WS2;
constexpr size_t SZ_WE3 = 8*SZ_WS3;
constexpr size_t SZ_WR  = (size_t)5*128*32*2;
constexpr size_t SZ_WIH = (size_t)1024*256*2;
constexpr size_t SZ_WHH = (size_t)128*1024*4;
constexpr size_t SZ_ACT0 = (size_t)B*T*32*2;
constexpr size_t SZ_RACT = (size_t)B*T*128*2;
constexpr size_t SZ_AMIX = (size_t)B*T*256*2;
constexpr size_t SZ_CONV = (size_t)NU*T*256*2;
constexpr size_t SZ_A1   = (size_t)NU*T*64*2;
constexpr size_t SZ_A2   = (size_t)NU*T*128*2;
constexpr size_t SZ_U    = (size_t)B*T*1024*2;     // aliases CONV+A1+A2
constexpr size_t SZ_STAT = (size_t)NU*8*2*4;
constexpr size_t SZ_STATR= (size_t)B*8*2*4;
constexpr size_t SZ_RH   = (size_t)B*128*4;
constexpr size_t SZ_EIDX = (size_t)B*2*4;
constexpr size_t SZ_SWT  = (size_t)B*2*4;
constexpr size_t SZ_HT   = (size_t)B*256*4;

constexpr size_t OFF_WS1  = 0;
constexpr size_t OFF_WS2  = OFF_WS1 + SZ_WS1;
constexpr size_t OFF_WS3  = OFF_WS2 + SZ_WS2;
constexpr size_t OFF_WE1  = OFF_WS3 + SZ_WS3;
constexpr size_t OFF_WE2  = OFF_WE1 + SZ_WE1;
constexpr size_t OFF_WE3  = OFF_WE2 + SZ_WE2;
constexpr size_t OFF_WR   = OFF_WE3 + SZ_WE3;
constexpr size_t OFF_WIH  = OFF_WR  + SZ_WR;
constexpr size_t OFF_WHH  = OFF_WIH + SZ_WIH;
constexpr size_t OFF_ACT0 = OFF_WHH + SZ_WHH;
constexpr size_t OFF_RACT = OFF_ACT0 + SZ_ACT0;
constexpr size_t OFF_AMIX = OFF_RACT + SZ_RACT;
constexpr size_t OFF_CONV = OFF_AMIX + SZ_AMIX;
constexpr size_t OFF_A1   = OFF_CONV + SZ_CONV;
constexpr size_t OFF_A2   = OFF_A1 + SZ_A1;
constexpr size_t OFF_U    = OFF_CONV;              // alias
constexpr size_t OFF_STAT = OFF_A2 + SZ_A2;
constexpr size_t OFF_STATR= OFF_STAT + SZ_STAT;
constexpr size_t OFF_RH   = OFF_STATR + SZ_STATR;
constexpr size_t OFF_EIDX = OFF_RH + SZ_RH;
constexpr size_t OFF_SWT  = OFF_EIDX + SZ_EIDX;
constexpr size_t OFF_HT   = OFF_SWT + SZ_SWT;
constexpr size_t WS_TOTAL = OFF_HT + SZ_HT;

static_assert(SZ_U <= SZ_CONV + SZ_A1 + SZ_A2, "U alias overflow");

DEVI float geluf(float x){ return 0.5f*x*(1.f + erff(x*0.70710678118654752f)); }
DEVI float fsig(float x){ return 1.f/(1.f + __expf(-x)); }
DEVI float ftanh(float x){ float e = __expf(-2.f*x); return (1.f-e)/(1.f+e); }

// ---------------------------------------------------------------------------
// Weight prep (unchanged, verified)
// ---------------------------------------------------------------------------
DEVI void fill_convw(f16* dst, const float* src, int COUT, int CI, int CIP, int idx){
  int s  = idx / (COUT*CIP);
  int r  = idx - s*(COUT*CIP);
  int co = r / CIP;
  int ci = r - co*CIP;
  float v = (ci < CI) ? src[((size_t)co*CI + ci)*5 + s] : 0.f;
  dst[idx] = (f16)v;
}

__global__ __launch_bounds__(256) void k_prep_w(
    const float* eW1, const float* eW2, const float* eW3,
    const float* sW1, const float* sW2, const float* sW3, const float* rW,
    const float* Wih, const float* Whh, char* ws)
{
  int i = blockIdx.x*256 + threadIdx.x;
  if (i < 10240){ fill_convw((f16*)(ws+OFF_WS1), sW1, 64, 16, 32, i); return; } i -= 10240;
  if (i < 40960){ fill_convw((f16*)(ws+OFF_WS2), sW2, 128, 64, 64, i); return; } i -= 40960;
  if (i < 163840){ fill_convw((f16*)(ws+OFF_WS3), sW3, 256, 128, 128, i); return; } i -= 163840;
  if (i < 81920){ int e=i/10240, r=i-e*10240;
    fill_convw((f16*)(ws+OFF_WE1)+ (size_t)e*10240, eW1 + (size_t)e*64*16*5, 64, 16, 32, r); return; } i -= 81920;
  if (i < 327680){ int e=i/40960, r=i-e*40960;
    fill_convw((f16*)(ws+OFF_WE2)+ (size_t)e*40960, eW2 + (size_t)e*128*64*5, 128, 64, 64, r); return; } i -= 327680;
  if (i < 1310720){ int e=i/163840, r=i-e*163840;
    fill_convw((f16*)(ws+OFF_WE3)+ (size_t)e*163840, eW3 + (size_t)e*163840, 256, 128, 128, r); return; } i -= 1310720;
  if (i < 20480){ fill_convw((f16*)(ws+OFF_WR), rW, 128, 16, 32, i); return; } i -= 20480;
  if (i < 262144){ // W_ih (256,1024) -> [j][k]
    int j = i >> 8, k = i & 255;
    ((f16*)(ws+OFF_WIH))[i] = (f16)Wih[(size_t)k*1024 + j]; return; } i -= 262144;
  if (i < 131072){ // W_hh -> packed row-pairs [pair][1024]
    int i2 = i >> 10, j = i & 1023;
    f16 a = (f16)Whh[(size_t)(2*i2)*1024 + j];
    f16 b = (f16)Whh[(size_t)(2*i2+1)*1024 + j];
    u32 u = (u32)__builtin_bit_cast(unsigned short, a)
          | ((u32)__builtin_bit_cast(unsigned short, b) << 16);
    ((u32*)(ws+OFF_WHH))[i] = u; return; }
}

__global__ __launch_bounds__(256) void k_prep_x(const float* __restrict__ x, char* ws){
  int idx = blockIdx.x*256 + threadIdx.x;
  if (idx >= B*T*32) return;
  int b = idx/(T*32); int r = idx - b*(T*32); int t = r >> 5; int c = r & 31;
  f16 v = (c < 16) ? (f16)x[((size_t)b*16 + c)*T + t] : (f16)0.f;
  ((f16*)(ws+OFF_ACT0))[idx] = v;
}

// ---------------------------------------------------------------------------
// Fused layer (verified R12/R14)
// ---------------------------------------------------------------------------
template<int CIN, int COUT_BLK, int CPG, bool GAP>
__global__ __launch_bounds__(512) void k_layer(
    const f16* __restrict__ act, long actUnitStride,
    const f16* __restrict__ wtS, const f16* __restrict__ wtE, long wtEStride,
    const int* __restrict__ eidx,
    const float* __restrict__ gS, const float* __restrict__ bS,
    const float* __restrict__ gE, const float* __restrict__ bE,
    int COUT_TOTAL,
    f16* __restrict__ outp, long outUnitStride, int outStride,
    float* __restrict__ rhOut)
{
  constexpr int CH8  = COUT_BLK/8;
  constexpr int NG   = COUT_BLK/CPG;
  constexpr int CPW  = CPG/8;
  constexpr int NF   = (COUT_BLK >= 64) ? 4 : COUT_BLK/16;
  constexpr int NPASS = COUT_BLK/(NF*16);
  constexpr int ROWSTEP = 512/CH8;
  constexpr int ITERS   = T/ROWSTEP;

  int u = blockIdx.x, hf = blockIdx.y;
  int s_ = u >> 6, b = u & 63;
  const f16* wt = wtS;
  const float* gamma = gS; const float* beta = bS;
  if (eidx && s_ < 2){
    int e = eidx[b*2 + s_];
    wt    = wtE + (size_t)e*wtEStride;
    gamma = gE + (size_t)e*COUT_TOTAL;
    beta  = bE + (size_t)e*COUT_TOTAL;
  }
  gamma += hf*COUT_BLK; beta += hf*COUT_BLK;
  const f16* abase = act + (actUnitStride ? (size_t)u*actUnitStride
                                          : (size_t)b*T*CIN);
  int wcol0 = hf*COUT_BLK;

  __shared__ f16 tile[T*COUT_BLK];
  __shared__ float cpart[8][CH8][2];
  __shared__ float mr[NG][2];
  __shared__ float gcol[GAP ? 8 : 1][GAP ? CH8 : 1][8];

  int tid = threadIdx.x;
  int wave = tid >> 6, lane = tid & 63;
  int lr = lane & 15, lk = lane >> 4;

  // ---- conv phase ----
  for (int mt = wave; mt < 32; mt += 8){
    int trow = mt*16 + lr;
    #pragma unroll
    for (int np = 0; np < NPASS; ++np){
      f32x4 acc[NF];
      #pragma unroll
      for (int nf=0; nf<NF; ++nf) acc[nf] = f32x4{0.f,0.f,0.f,0.f};
      #pragma unroll
      for (int sh = 0; sh < 5; ++sh){
        int tg = trow + sh - 2;
        bool valid = (unsigned)tg < (unsigned)T;
        const f16* arow = abase + (long)tg*CIN + lk*8;
        #pragma unroll
        for (int c0=0; c0<CIN; c0+=32){
          f16x8 af = {(f16)0,(f16)0,(f16)0,(f16)0,(f16)0,(f16)0,(f16)0,(f16)0};
          if (valid) af = *(const f16x8*)(arow + c0);
          #pragma unroll
          for (int nf=0; nf<NF; ++nf){
            int col = wcol0 + np*NF*16 + nf*16 + lr;
            f16x8 bf = *(const f16x8*)(wt + ((size_t)sh*COUT_TOTAL + col)*CIN + c0 + lk*8);
            acc[nf] = __builtin_amdgcn_mfma_f32_16x16x32_f16(af, bf, acc[nf], 0, 0, 0);
          }
        }
      }
      #pragma unroll
      for (int nf=0; nf<NF; ++nf)
        #pragma unroll
        for (int r=0; r<4; ++r)
          tile[(size_t)(mt*16 + lk*4 + r)*COUT_BLK + np*NF*16 + nf*16 + lr] = (f16)acc[nf][r];
    }
  }
  __syncthreads();

  // ---- stats phase ----
  int chunk = tid & (CH8-1);
  int row0  = tid / CH8;
  float sum = 0.f, ss = 0.f;
  #pragma unroll
  for (int k=0; k<ITERS; ++k){
    int row = row0 + k*ROWSTEP;
    f16x8 xv = *(const f16x8*)(tile + (size_t)row*COUT_BLK + chunk*8);
    #pragma unroll
    for (int e=0;e<8;++e){ float f = (float)xv[e]; sum += f; ss += f*f; }
  }
  #pragma unroll
  for (int mk=CH8; mk<=32; mk<<=1){ sum += __shfl_xor(sum, mk); ss += __shfl_xor(ss, mk); }
  if (lane < CH8){ cpart[wave][lane][0] = sum; cpart[wave][lane][1] = ss; }
  __syncthreads();
  if (tid < NG){
    float S = 0.f, Q = 0.f;
    for (int w2=0; w2<8; ++w2)
      for (int cc=0; cc<CPW; ++cc){ S += cpart[w2][tid*CPW+cc][0]; Q += cpart[w2][tid*CPW+cc][1]; }
    constexpr float N = (float)(CPG*T);
    float m = S/N, var = Q/N - m*m;
    mr[tid][0] = m; mr[tid][1] = rsqrtf(var + 1e-5f);
  }
  __syncthreads();

  // ---- apply phase ----
  int g = chunk / CPW;
  float m = mr[g][0], rstd = mr[g][1];
  float gm[8], bt[8];
  #pragma unroll
  for (int e=0;e<8;++e){ gm[e] = gamma[chunk*8+e]; bt[e] = beta[chunk*8+e]; }
  float cs[8] = {0.f,0.f,0.f,0.f,0.f,0.f,0.f,0.f};
  f16* obase = outp ? (outp + (size_t)u*outUnitStride + hf*COUT_BLK) : nullptr;
  #pragma unroll
  for (int k=0; k<ITERS; ++k){
    int row = row0 + k*ROWSTEP;
    f16x8 xv = *(const f16x8*)(tile + (size_t)row*COUT_BLK + chunk*8);
    f16x8 h8;
    #pragma unroll
    for (int e=0;e<8;++e){
      float xn = ((float)xv[e]-m)*rstd*gm[e] + bt[e];
      float o = geluf(xn);
      if constexpr (GAP) cs[e] += o; else h8[e] = (f16)o;
    }
    if constexpr (!GAP)
      *(f16x8*)(obase + (size_t)row*outStride + chunk*8) = h8;
  }
  if constexpr (GAP){
    #pragma unroll
    for (int mk=CH8; mk<=32; mk<<=1)
      #pragma unroll
      for (int e=0;e<8;++e) cs[e] += __shfl_xor(cs[e], mk);
    if (lane < CH8)
      #pragma unroll
      for (int e=0;e<8;++e) gcol[wave][lane][e] = cs[e];
    __syncthreads();
    if (tid < COUT_BLK){
      int c = tid >> 3, e = tid & 7;
      float tot = 0.f;
      for (int w2=0; w2<8; ++w2) tot += gcol[w2][c][e];
      rhOut[b*128 + hf*COUT_BLK + tid] = tot * (1.f/(float)T);
    }
  }
}

// ---------------------------------------------------------------------------
// Fused mix + W_ih GEMM (verified R13/R14)
// ---------------------------------------------------------------------------
__global__ __launch_bounds__(512) void k_convmix(
    const f16* __restrict__ conv, const float* __restrict__ swt,
    const f16* __restrict__ wih, const float* __restrict__ bias,
    f16* __restrict__ U)
{
  int tt = blockIdx.x;
  int b  = blockIdx.y;
  int t0 = tt*64;

  __shared__ f16 amixT[64][264];

  float w0 = swt[b*2], w1 = swt[b*2+1];
  const f16* s0 = conv + (size_t)b*T*256;
  const f16* s1 = conv + (size_t)(64+b)*T*256;
  const f16* s2 = conv + (size_t)(128+b)*T*256;

  int tid = threadIdx.x;
  for (int i = tid; i < 64*32; i += 512){
    int row = i >> 5, ch = i & 31;
    size_t off = (size_t)(t0+row)*256 + ch*8;
    f16x8 x0 = *(const f16x8*)(s0+off);
    f16x8 x1 = *(const f16x8*)(s1+off);
    f16x8 x2 = *(const f16x8*)(s2+off);
    f16x8 h8;
    #pragma unroll
    for (int e=0;e<8;++e)
      h8[e] = (f16)(w0*(float)x0[e] + w1*(float)x1[e] + (float)x2[e]);
    *(f16x8*)(&amixT[row][ch*8]) = h8;
  }
  __syncthreads();

  int wave = tid >> 6, lane = tid & 63;
  int lr = lane & 15, lk = lane >> 4;
  f16* ob = U + ((size_t)b*T + t0)*1024;

  for (int tk = wave; tk < 64; tk += 8){
    int mtile = tk >> 4, panel = tk & 15;
    int n0 = panel*64;
    f32x4 acc[4];
    #pragma unroll
    for (int nf=0; nf<4; ++nf) acc[nf] = f32x4{0.f,0.f,0.f,0.f};
    #pragma unroll
    for (int c0=0; c0<256; c0+=32){
      f16x8 af = *(const f16x8*)(&amixT[mtile*16 + lr][c0 + lk*8]);
      #pragma unroll
      for (int nf=0; nf<4; ++nf){
        int col = n0 + nf*16 + lr;
        f16x8 bf = *(const f16x8*)(wih + (size_t)col*256 + c0 + lk*8);
        acc[nf] = __builtin_amdgcn_mfma_f32_16x16x32_f16(af, bf, acc[nf], 0, 0, 0);
      }
    }
    #pragma unroll
    for (int nf=0; nf<4; ++nf){
      int col = n0 + nf*16 + lr;
      float bv = bias[col];
      #pragma unroll
      for (int r=0; r<4; ++r){
        int trw = mtile*16 + lk*4 + r;
        ob[(size_t)trw*1024 + col] = (f16)(acc[nf][r] + bv);
      }
    }
  }
}

// ---------------------------------------------------------------------------
// Router MLP (unchanged, verified)
// ---------------------------------------------------------------------------
__global__ __launch_bounds__(128) void k_router(
    const float* __restrict__ rh,
    const float* __restrict__ m1W, const float* __restrict__ m1b,
    const float* __restrict__ lng, const float* __restrict__ lnb,
    const float* __restrict__ m2W, const float* __restrict__ m2b,
    const float* __restrict__ gW,  const float* __restrict__ gb,
    int* __restrict__ eidx, float* __restrict__ swt)
{
  int b = blockIdx.x, j = threadIdx.x;
  __shared__ float sbuf[128];
  __shared__ float red[4];
  __shared__ float z2[64];
  sbuf[j] = rh[b*128 + j];
  __syncthreads();
  float acc = m1b[j];
  for (int k=0; k<128; ++k) acc += sbuf[k]*m1W[k*128 + j];
  float s1 = acc, s2 = acc*acc;
  #pragma unroll
  for (int off=32; off; off>>=1){ s1 += __shfl_down(s1, off); s2 += __shfl_down(s2, off); }
  int wid = j >> 6, lane = j & 63;
  if (lane == 0){ red[wid] = s1; red[2+wid] = s2; }
  __syncthreads();
  float S = red[0]+red[1], Q = red[2]+red[3];
  float m = S*(1.f/128.f), var = Q*(1.f/128.f) - m*m;
  float xn = (acc - m)*rsqrtf(var + 1e-5f)*lng[j] + lnb[j];
  float ge = geluf(xn);
  __syncthreads();
  sbuf[j] = ge;
  __syncthreads();
  if (j < 64){
    float a = m2b[j];
    for (int k=0; k<128; ++k) a += sbuf[k]*m2W[k*64 + j];
    z2[j] = a;
  }
  __syncthreads();
  if (j == 0){
    float lg[8];
    for (int e=0; e<8; ++e){
      float a = gb[e];
      for (int k=0; k<64; ++k) a += z2[k]*gW[k*8 + e];
      lg[e] = a;
    }
    float mx = lg[0];
    for (int e=1; e<8; ++e) mx = fmaxf(mx, lg[e]);
    float p[8], sum = 0.f;
    for (int e=0; e<8; ++e){ p[e] = __expf(lg[e]-mx); sum += p[e]; }
    float inv = 1.f/sum;
    for (int e=0; e<8; ++e) p[e] *= inv;
    int i1 = 0;
    for (int e=1; e<8; ++e) if (p[e] > p[i1]) i1 = e;
    int i2 = -1;
    for (int e=0; e<8; ++e){ if (e==i1) continue; if (i2 < 0 || p[e] > p[i2]) i2 = e; }
    float s = p[i1] + p[i2] + 1e-9f;
    eidx[b*2]   = i1;  swt[b*2]   = p[i1]/s;
    eidx[b*2+1] = i2;  swt[b*2+1] = p[i2]/s;
  }
}

// ---------------------------------------------------------------------------
// Persistent LSTM — verified optimum (863us, 4x reproduced): 64 WGs x 512 thr,
// PV5=100 VGPR pairs/col + PLQ=7 LDS quads/col.
// ---------------------------------------------------------------------------
constexpr int PV5 = 100;
constexpr int PLQ = 7;

DEVI float dot2acc(u32 wu, u32 hu, float acc){
#if __has_builtin(__builtin_amdgcn_fdot2)
  return __builtin_amdgcn_fdot2(__builtin_bit_cast(f16x2, wu),
                                __builtin_bit_cast(f16x2, hu), acc, false);
#else
  f16x2 a = __builtin_bit_cast(f16x2, wu), b = __builtin_bit_cast(f16x2, hu);
  return acc + (float)a.x*(float)b.x + (float)a.y*(float)b.y;
#endif
}

__global__ __attribute__((amdgpu_flat_work_group_size(512,512), amdgpu_waves_per_eu(2,2)))
void k_lstm(const u32* __restrict__ whh, const f16* __restrict__ U,
            float* __restrict__ hTout)
{
  int b = blockIdx.x, j = threadIdx.x;
  int d = j & 255, half = j >> 8;
  int colA = half*256 + d;
  int colB = 512 + colA;

  __shared__ u32 wl[PLQ*4*1024];              // 112 KB: pairs [100,128)
  __shared__ __align__(16) u32 hbuf[2][128];
  __shared__ float gbF[256], gbO[256];

  u32 wA[PV5], wB[PV5];
  #pragma unroll
  for (int i=0; i<PV5; ++i){
    wA[i] = whh[(size_t)i*1024 + colA];
    wB[i] = whh[(size_t)i*1024 + colB];
  }
  for (int idx = j; idx < PLQ*4*1024; idx += 512){
    int p = idx >> 10, c = idx & 1023;
    wl[idx] = whh[(size_t)(PV5+p)*1024 + c];
  }
  if (j < 128) hbuf[0][j] = 0u;

  float cst = 0.f, hst = 0.f;
  const f16* Ub = U + (size_t)b*T*1024;
  float uA = (float)Ub[colA], uB = (float)Ub[colB];
  __syncthreads();

  int cur = 0;
  for (int t=0; t<T; ++t){
    float aA = uA, aB = uB;
    if (t+1 < T){
      const f16* un = Ub + (size_t)(t+1)*1024;
      uA = (float)un[colA]; uB = (float)un[colB];
    }
    const uint4* hp4 = (const uint4*)hbuf[cur];
    #pragma unroll
    for (int q=0; q<PV5/4; ++q){
      uint4 hq = hp4[q];
      aA = dot2acc(wA[4*q+0], hq.x, aA); aB = dot2acc(wB[4*q+0], hq.x, aB);
      aA = dot2acc(wA[4*q+1], hq.y, aA); aB = dot2acc(wB[4*q+1], hq.y, aB);
      aA = dot2acc(wA[4*q+2], hq.z, aA); aB = dot2acc(wB[4*q+2], hq.z, aB);
      aA = dot2acc(wA[4*q+3], hq.w, aA); aB = dot2acc(wB[4*q+3], hq.w, aB);
    }
    #pragma unroll
    for (int k=0; k<PLQ; ++k){
      uint4 hq = hp4[PV5/4 + k];
      u32 a0 = wl[(4*k+0)*1024 + colA], b0 = wl[(4*k+0)*1024 + colB];
      u32 a1 = wl[(4*k+1)*1024 + colA], b1 = wl[(4*k+1)*1024 + colB];
      u32 a2 = wl[(4*k+2)*1024 + colA], b2 = wl[(4*k+2)*1024 + colB];
      u32 a3 = wl[(4*k+3)*1024 + colA], b3 = wl[(4*k+3)*1024 + colB];
      aA = dot2acc(a0, hq.x, aA); aB = dot2acc(b0, hq.x, aB);
      aA = dot2acc(a1, hq.y, aA); aB = dot2acc(b1, hq.y, aB);
      aA = dot2acc(a2, hq.z, aA); aB = dot2acc(b2, hq.z, aB);
      aA = dot2acc(a3, hq.w, aA); aB = dot2acc(b3, hq.w, aB);
    }
    if (half){ gbF[d] = aA; gbO[d] = aB; }
    __syncthreads();
    if (!half){
      float gi = aA, gg = aB, gf = gbF[d], go = gbO[d];
      cst = fsig(gf)*cst + fsig(gi)*ftanh(gg);
      hst = fsig(go)*ftanh(cst);
      u16* hn = (u16*)hbuf[cur^1];
      hn[d] = __builtin_bit_cast(u16, (f16)hst);
    }
    __syncthreads();
    cur ^= 1;
  }
  if (!half) hTout[b*256 + d] = hst;
}

__global__ __launch_bounds__(256) void k_head(const float* __restrict__ hT,
    const float* __restrict__ Wc, const float* __restrict__ bc,
    float* __restrict__ out)
{
  int b = blockIdx.x, j = threadIdx.x;
  __shared__ float hs[256];
  hs[j] = hT[b*256 + j];
  __syncthreads();
  if (j < NC){
    float a = bc[j];
    for (int k=0; k<256; ++k) a += hs[k]*Wc[k*NC + j];
    out[b*NC + j] = a;
  }
}

// ---------------------------------------------------------------------------
extern "C" void kernel_launch(void* const* d_in, const int* in_sizes, int n_in,
                              void* d_out, int out_size, void* d_ws, size_t ws_size,
                              hipStream_t stream)
{
  if (ws_size < WS_TOTAL) return;

  const float* x    = (const float*)d_in[0];
  const float* eW1  = (const float*)d_in[1];
  const float* eg1  = (const float*)d_in[2];
  const float* eb1  = (const float*)d_in[3];
  const float* eW2  = (const float*)d_in[4];
  const float* eg2  = (const float*)d_in[5];
  const float* eb2  = (const float*)d_in[6];
  const float* eW3  = (const float*)d_in[7];
  const float* eg3  = (const float*)d_in[8];
  const float* eb3  = (const float*)d_in[9];
  const float* sW1  = (const float*)d_in[10];
  const float* sg1  = (const float*)d_in[11];
  const float* sb1  = (const float*)d_in[12];
  const float* sW2  = (const float*)d_in[13];
  const float* sg2  = (const float*)d_in[14];
  const float* sb2  = (const float*)d_in[15];
  const float* sW3  = (const float*)d_in[16];
  const float* sg3  = (const float*)d_in[17];
  const float* sb3  = (const float*)d_in[18];
  const float* rW   = (const float*)d_in[19];
  const float* rg   = (const float*)d_in[20];
  const float* rb   = (const float*)d_in[21];
  const float* rm1W = (const float*)d_in[22];
  const float* rm1b = (const float*)d_in[23];
  const float* rlng = (const float*)d_in[24];
  const float* rlnb = (const float*)d_in[25];
  const float* rm2W = (const float*)d_in[26];
  const float* rm2b = (const float*)d_in[27];
  const float* gW   = (const float*)d_in[28];
  const float* gb   = (const float*)d_in[29];
  const float* Wih  = (const float*)d_in[30];
  const float* Whh  = (const float*)d_in[31];
  const float* blst = (const float*)d_in[32];
  const float* Wc   = (const float*)d_in[33];
  const float* bc   = (const float*)d_in[34];

  char* ws = (char*)d_ws;
  f16*  ws1   = (f16*)(ws + OFF_WS1);
  f16*  ws2   = (f16*)(ws + OFF_WS2);
  f16*  ws3   = (f16*)(ws + OFF_WS3);
  f16*  we1   = (f16*)(ws + OFF_WE1);
  f16*  we2   = (f16*)(ws + OFF_WE2);
  f16*  we3   = (f16*)(ws + OFF_WE3);
  f16*  wr    = (f16*)(ws + OFF_WR);
  f16*  wih   = (f16*)(ws + OFF_WIH);
  u32*  whh   = (u32*)(ws + OFF_WHH);
  f16*  act0  = (f16*)(ws + OFF_ACT0);
  f16*  convb = (f16*)(ws + OFF_CONV);
  f16*  a1    = (f16*)(ws + OFF_A1);
  f16*  a2    = (f16*)(ws + OFF_A2);
  f16*  Ubuf  = (f16*)(ws + OFF_U);
  float* rh    = (float*)(ws + OFF_RH);
  int*   eidx  = (int*)(ws + OFF_EIDX);
  float* swt   = (float*)(ws + OFF_SWT);
  float* hTb   = (float*)(ws + OFF_HT);

  // ---- prep ----
  k_prep_w<<<(2349056 + 255)/256, 256, 0, stream>>>(eW1,eW2,eW3,sW1,sW2,sW3,rW,Wih,Whh,ws);
  k_prep_x<<<(B*T*32 + 255)/256, 256, 0, stream>>>(x, ws);

  // ---- router: fused conv+GN+GELU+GAP (2 chan-halves) -> rh -> MLP ----
  k_layer<32,64,16,true><<<dim3(64,2), 512, 0, stream>>>(
      act0, 0L, wr, nullptr, 0L, nullptr, rg, rb, nullptr, nullptr, 128,
      nullptr, 0L, 0, rh);
  k_router<<<B, 128, 0, stream>>>(rh, rm1W, rm1b, rlng, rlnb, rm2W, rm2b, gW, gb, eidx, swt);

  // ---- fused layers (channel-split grids: 384/384/768 blocks) ----
  k_layer<32,32,8,false><<<dim3(NU,2), 512, 0, stream>>>(
      act0, 0L, ws1, we1, (long)(5*64*32), eidx, sg1, sb1, eg1, eb1, 64,
      a1, (long)T*64, 64, nullptr);
  k_layer<64,64,16,false><<<dim3(NU,2), 512, 0, stream>>>(
      a1, (long)T*64, ws2, we2, (long)(5*128*64), eidx, sg2, sb2, eg2, eb2, 128,
      a2, (long)T*128, 128, nullptr);
  k_layer<128,64,32,false><<<dim3(NU,4), 512, 0, stream>>>(
      a2, (long)T*128, ws3, we3, (long)(5*256*128), eidx, sg3, sb3, eg3, eb3, 256,
      convb, (long)T*256, 256, nullptr);

  // ---- fused mix + W_ih GEMM -> U ----
  k_convmix<<<dim3(8,64), 512, 0, stream>>>(convb, swt, wih, blst, Ubuf);

  // ---- LSTM ----
  k_lstm<<<B, 512, 0, stream>>>(whh, Ubuf, hTb);
  k_head<<<B, 256, 0, stream>>>(hTb, Wc, bc, (float*)d_out);
}